// Round 15
// baseline (383.762 us; speedup 1.0000x reference)
//
#include <hip/hip_runtime.h>
#include <hip/hip_bf16.h>

typedef __attribute__((ext_vector_type(8))) short s16x8;
typedef __attribute__((ext_vector_type(4))) float f32x4;
typedef __attribute__((ext_vector_type(2))) float f32x2;

__device__ inline unsigned int f2bf(float f) {
    union { float f; unsigned int i; } v;
    v.f = f;
    return (v.i + 0x7FFFu + ((v.i >> 16) & 1u)) >> 16;   // RNE
}
__device__ inline unsigned char f2fp8(float v) {
    const int p = __builtin_amdgcn_cvt_pk_fp8_f32(v, v, 0, false);
    return (unsigned char)(p & 0xFF);
}

// ---------- prep: weight transposes (bf16) + bias concat ----------
__global__ __launch_bounds__(256) void prep_w(
    const float* __restrict__ Wq, const float* __restrict__ Wk,
    const float* __restrict__ W1, const float* __restrict__ W2,
    const float* __restrict__ Wp,
    const float* __restrict__ bq, const float* __restrict__ bk,
    const float* __restrict__ b1,
    unsigned short* __restrict__ Wtqkt, unsigned short* __restrict__ Wt2,
    unsigned short* __restrict__ Wtp, float* __restrict__ bqkt)
{
    const int tid = threadIdx.x;
    int b = blockIdx.x;
    if (b < 1024) {                          // 4 x 256x256 weights
        const int w = b >> 8;
        const int i = (b & 255) * 256 + tid;
        const int k = i >> 8, j = i & 255;   // coalesced read of W[k][j]
        const float* W = (w == 0) ? Wq : (w == 1) ? Wk : (w == 2) ? W1 : W2;
        unsigned short* dst = (w == 3) ? Wt2 : (Wtqkt + w * 65536);
        dst[j * 256 + k] = (unsigned short)f2bf(W[i]);
        return;
    }
    b -= 1024;
    if (b < 512) {                           // Wpred [256][512] -> Wtp [512][256]
        const int i = b * 256 + tid;
        const int k = i >> 9, j = i & 511;
        Wtp[(size_t)j * 256 + k] = (unsigned short)f2bf(Wp[i]);
        return;
    }
    b -= 512;
    {                                        // bqkt = [bq | bk | b1]
        const int i = b * 256 + tid;
        bqkt[i] = (i < 256) ? bq[i] : (i < 512) ? bk[i - 256] : b1[i - 512];
    }
}

// ---------- fused node pipeline, one dispatch ----------
// Packed tables: qhp[N][768] = [q fp8 (256) | hp fp8 (512)]
//               kgp[N][768] = [k fp8 (256) | gp fp8 (512)]
__global__ __launch_bounds__(256) void gemm_fused(
    const float* __restrict__ z, const float* __restrict__ h,
    const unsigned short* __restrict__ Wtqkt, const unsigned short* __restrict__ Wt2,
    const unsigned short* __restrict__ Wtp,
    const float* __restrict__ bqkt, const float* __restrict__ b2,
    unsigned char* __restrict__ qhp, unsigned char* __restrict__ kgp, int M)
{
    __shared__ __align__(16) char smem[65536];
    char* ldsA = smem;
    char* ldsB = smem + 32768;

    const int tid  = threadIdx.x;
    const int wid  = tid >> 6, lane = tid & 63;
    const int wr   = wid >> 1, wc = wid & 1;
    const int r0   = blockIdx.x * 64;
    const int swz  = (lane & 7) << 4;
    const int ro   = lane & 15, ko = (lane >> 4) * 16;
    const int lr0  = wr * 32 + (lane >> 4) * 4;       // local row base of C frags
    const int baseA0 = (wr * 32 +  0 + ro) * 512 + ko;
    const int baseA1 = (wr * 32 + 16 + ro) * 512 + ko;
    const int baseB0 = (wc * 32 +  0 + ro) * 512 + ko;
    const int baseB1 = (wc * 32 + 16 + ro) * 512 + ko;

    f32x4 a00, a01, a10, a11;

    auto stageAf = [&](const float* Af) {
        for (int i = tid; i < 2048; i += 256) {
            const int row = i >> 5, off = i & 31;
            const int gr = r0 + row;
            uint4 v = make_uint4(0, 0, 0, 0);
            if (gr < M) {
                const float4 a = *(const float4*)(Af + (size_t)gr * 256 + off * 8);
                const float4 c = *(const float4*)(Af + (size_t)gr * 256 + off * 8 + 4);
                v.x = f2bf(a.x) | (f2bf(a.y) << 16);
                v.y = f2bf(a.z) | (f2bf(a.w) << 16);
                v.z = f2bf(c.x) | (f2bf(c.y) << 16);
                v.w = f2bf(c.z) | (f2bf(c.w) << 16);
            }
            *(uint4*)(ldsA + ((row * 512 + off * 16) ^ ((row & 7) << 4))) = v;
        }
    };

    auto chunk = [&](const unsigned short* Wt, int rowbase) {
        for (int i = tid; i < 2048; i += 256) {
            const int row = i >> 5, off = i & 31;
            const uint4 v = *(const uint4*)(Wt + (size_t)(rowbase + row) * 256 + off * 8);
            *(uint4*)(ldsB + ((row * 512 + off * 16) ^ ((row & 7) << 4))) = v;
        }
        __syncthreads();
        a00 = (f32x4){0,0,0,0}; a01 = (f32x4){0,0,0,0};
        a10 = (f32x4){0,0,0,0}; a11 = (f32x4){0,0,0,0};
#pragma unroll
        for (int kk = 0; kk < 8; ++kk) {
            const int kb = kk * 64;
            const s16x8 x0 = *(const s16x8*)(ldsA + ((baseA0 + kb) ^ swz));
            const s16x8 x1 = *(const s16x8*)(ldsA + ((baseA1 + kb) ^ swz));
            const s16x8 y0 = *(const s16x8*)(ldsB + ((baseB0 + kb) ^ swz));
            const s16x8 y1 = *(const s16x8*)(ldsB + ((baseB1 + kb) ^ swz));
            a00 = __builtin_amdgcn_mfma_f32_16x16x32_bf16(x0, y0, a00, 0, 0, 0);
            a01 = __builtin_amdgcn_mfma_f32_16x16x32_bf16(x0, y1, a01, 0, 0, 0);
            a10 = __builtin_amdgcn_mfma_f32_16x16x32_bf16(x1, y0, a10, 0, 0, 0);
            a11 = __builtin_amdgcn_mfma_f32_16x16x32_bf16(x1, y1, a11, 0, 0, 0);
        }
    };

    auto store_fp8 = [&](unsigned char* outb, int obase, const float* bias) {
        const int cb = wc * 32;
        const float bs0 = bias ? bias[cb + ro] : 0.0f;
        const float bs1 = bias ? bias[cb + 16 + ro] : 0.0f;
        const int gr0 = r0 + lr0, gr1 = gr0 + 16;
        const int col0 = obase + cb + ro, col1 = obase + cb + 16 + ro;
#pragma unroll
        for (int r = 0; r < 4; ++r) {
            if (gr0 + r < M) {
                outb[(size_t)(gr0 + r) * 768 + col0] = f2fp8(a00[r] + bs0);
                outb[(size_t)(gr0 + r) * 768 + col1] = f2fp8(a01[r] + bs1);
            }
            if (gr1 + r < M) {
                outb[(size_t)(gr1 + r) * 768 + col0] = f2fp8(a10[r] + bs0);
                outb[(size_t)(gr1 + r) * 768 + col1] = f2fp8(a11[r] + bs1);
            }
        }
        __syncthreads();
    };

    auto frag_to_ldsA = [&](const unsigned int* treg) {
#pragma unroll
        for (int tc = 0; tc < 4; ++tc) {
            const int cb = tc * 64 + wc * 32;
#pragma unroll
            for (int r = 0; r < 4; ++r) {
                const unsigned int w0 = treg[tc * 8 + r * 2];
                const unsigned int w1 = treg[tc * 8 + r * 2 + 1];
                const int row0 = lr0 + r, row1 = row0 + 16;
                *(unsigned short*)(ldsA + ((row0 * 512 + (cb + ro) * 2)      ^ ((row0 & 7) << 4))) = (unsigned short)(w0 & 0xFFFFu);
                *(unsigned short*)(ldsA + ((row0 * 512 + (cb + 16 + ro) * 2) ^ ((row0 & 7) << 4))) = (unsigned short)(w0 >> 16);
                *(unsigned short*)(ldsA + ((row1 * 512 + (cb + ro) * 2)      ^ ((row1 & 7) << 4))) = (unsigned short)(w1 & 0xFFFFu);
                *(unsigned short*)(ldsA + ((row1 * 512 + (cb + 16 + ro) * 2) ^ ((row1 & 7) << 4))) = (unsigned short)(w1 >> 16);
            }
        }
    };

    if (blockIdx.y == 1) {
        stageAf(h);
        for (int c = 0; c < 8; ++c) { chunk(Wtp, c * 64); store_fp8(qhp, 256 + c * 64, nullptr); }
        return;
    }

    // ---- z-path ----
    stageAf(z);
    for (int c = 0; c < 4; ++c) { chunk(Wtqkt, c * 64);        store_fp8(qhp, c * 64, bqkt + c * 64); }
    for (int c = 0; c < 4; ++c) { chunk(Wtqkt, 256 + c * 64);  store_fp8(kgp, c * 64, bqkt + 256 + c * 64); }

    unsigned int treg[32];
#pragma unroll
    for (int tc = 0; tc < 4; ++tc) {
        chunk(Wtqkt, 512 + tc * 64);
        const int cb = tc * 64 + wc * 32;
        const float bs0 = bqkt[512 + cb + ro];
        const float bs1 = bqkt[512 + cb + 16 + ro];
#pragma unroll
        for (int r = 0; r < 4; ++r) {
            treg[tc * 8 + r * 2]     = f2bf(fmaxf(a00[r] + bs0, 0.0f)) | (f2bf(fmaxf(a01[r] + bs1, 0.0f)) << 16);
            treg[tc * 8 + r * 2 + 1] = f2bf(fmaxf(a10[r] + bs0, 0.0f)) | (f2bf(fmaxf(a11[r] + bs1, 0.0f)) << 16);
        }
        __syncthreads();
    }
    frag_to_ldsA(treg);
    __syncthreads();

#pragma unroll
    for (int gc = 0; gc < 4; ++gc) {
        chunk(Wt2, gc * 64);
        const int cb = gc * 64 + wc * 32;
        const float bs0 = b2[cb + ro];
        const float bs1 = b2[cb + 16 + ro];
#pragma unroll
        for (int r = 0; r < 4; ++r) {
            treg[gc * 8 + r * 2]     = f2bf(a00[r] + bs0) | (f2bf(a01[r] + bs1) << 16);
            treg[gc * 8 + r * 2 + 1] = f2bf(a10[r] + bs0) | (f2bf(a11[r] + bs1) << 16);
        }
        __syncthreads();
    }
    frag_to_ldsA(treg);
    __syncthreads();

    for (int c = 0; c < 8; ++c) { chunk(Wtp, c * 64); store_fp8(kgp, 256 + c * 64, nullptr); }
}

// ---------- edge kernel: persistent grid-stride, one wave/edge-iteration, nt stores ----------
__global__ __launch_bounds__(256) void edge_fused(
    const unsigned char* __restrict__ qhp, const unsigned char* __restrict__ kgp,
    const float* __restrict__ bpred,
    const int* __restrict__ edge_src, const int* __restrict__ node_ids,
    const int* __restrict__ masked_idx, const int* __restrict__ edge_idx,
    float* __restrict__ out, int P)
{
    const int wave = threadIdx.x >> 6;
    const int lane = threadIdx.x & 63;
    const int stride = gridDim.x * 4;

    const float4 bp0 = *(const float4*)&bpred[lane * 8];
    const float4 bp1 = *(const float4*)&bpred[lane * 8 + 4];

    for (int e = blockIdx.x * 4 + wave; e < P; e += stride) {
        const int mi = masked_idx[e];
        const int c  = node_ids[mi];
        const int s  = edge_src[edge_idx[e]];

        const unsigned char* rc = qhp + (size_t)c * 768;
        const unsigned char* rs = kgp + (size_t)s * 768;

        const unsigned int qw = *(const unsigned int*)(rc + lane * 4);
        const unsigned int kw = *(const unsigned int*)(rs + lane * 4);
        const f32x2 q01 = __builtin_amdgcn_cvt_pk_f32_fp8(qw, false);
        const f32x2 q23 = __builtin_amdgcn_cvt_pk_f32_fp8(qw, true);
        const f32x2 k01 = __builtin_amdgcn_cvt_pk_f32_fp8(kw, false);
        const f32x2 k23 = __builtin_amdgcn_cvt_pk_f32_fp8(kw, true);
        float dot = q01.x * k01.x + q01.y * k01.y + q23.x * k23.x + q23.y * k23.y;
#pragma unroll
        for (int off = 32; off; off >>= 1) dot += __shfl_xor(dot, off, 64);

        const float a = 1.0f / (1.0f + expf(-dot));
        const float oma = 1.0f - a;

        const uint2 hv = *(const uint2*)(rc + 256 + lane * 8);
        const uint2 gv = *(const uint2*)(rs + 256 + lane * 8);

        const f32x2 h0 = __builtin_amdgcn_cvt_pk_f32_fp8(hv.x, false);
        const f32x2 h1 = __builtin_amdgcn_cvt_pk_f32_fp8(hv.x, true);
        const f32x2 h2 = __builtin_amdgcn_cvt_pk_f32_fp8(hv.y, false);
        const f32x2 h3 = __builtin_amdgcn_cvt_pk_f32_fp8(hv.y, true);
        const f32x2 g0 = __builtin_amdgcn_cvt_pk_f32_fp8(gv.x, false);
        const f32x2 g1 = __builtin_amdgcn_cvt_pk_f32_fp8(gv.x, true);
        const f32x2 g2 = __builtin_amdgcn_cvt_pk_f32_fp8(gv.y, false);
        const f32x2 g3 = __builtin_amdgcn_cvt_pk_f32_fp8(gv.y, true);

        f32x4 r0, r1;
        r0[0] = fmaf(a, h0.x, fmaf(oma, g0.x, bp0.x));
        r0[1] = fmaf(a, h0.y, fmaf(oma, g0.y, bp0.y));
        r0[2] = fmaf(a, h1.x, fmaf(oma, g1.x, bp0.z));
        r0[3] = fmaf(a, h1.y, fmaf(oma, g1.y, bp0.w));
        r1[0] = fmaf(a, h2.x, fmaf(oma, g2.x, bp1.x));
        r1[1] = fmaf(a, h2.y, fmaf(oma, g2.y, bp1.y));
        r1[2] = fmaf(a, h3.x, fmaf(oma, g3.x, bp1.z));
        r1[3] = fmaf(a, h3.y, fmaf(oma, g3.y, bp1.w));

        float* dst = &out[(size_t)e * 512 + lane * 8];
        __builtin_nontemporal_store(r0, (f32x4*)dst);
        __builtin_nontemporal_store(r1, (f32x4*)(dst + 4));

        if (lane == 0) {
            __builtin_nontemporal_store((float)mi, &out[(size_t)P * 512 + e]);
        }
    }
}

extern "C" void kernel_launch(void* const* d_in, const int* in_sizes, int n_in,
                              void* d_out, int out_size, void* d_ws, size_t ws_size,
                              hipStream_t stream) {
    const float* h_mask = (const float*)d_in[0];
    const float* z      = (const float*)d_in[1];
    const float* Wq     = (const float*)d_in[2];
    const float* bq     = (const float*)d_in[3];
    const float* Wk     = (const float*)d_in[4];
    const float* bk     = (const float*)d_in[5];
    const float* W1     = (const float*)d_in[6];
    const float* b1     = (const float*)d_in[7];
    const float* W2     = (const float*)d_in[8];
    const float* b2     = (const float*)d_in[9];
    const float* Wpred  = (const float*)d_in[10];
    const float* bpred  = (const float*)d_in[11];
    const int* edge_index = (const int*)d_in[12];
    const int* node_ids   = (const int*)d_in[13];
    const int* masked_idx = (const int*)d_in[14];
    const int* edge_idx   = (const int*)d_in[15];

    const int N = in_sizes[13];
    const int P = in_sizes[14];

    // ---- workspace layout ----
    unsigned char*  qhp   = (unsigned char*)d_ws;                  // [N][768] fp8 = q|hp
    unsigned char*  kgp   = qhp + (size_t)N * 768;                 // [N][768] fp8 = k|gp
    unsigned short* Wtqkt = (unsigned short*)(kgp + (size_t)N * 768);  // [768][256] bf16
    unsigned short* Wt2   = Wtqkt + 196608;                        // [256][256]
    unsigned short* Wtp   = Wt2   + 65536;                         // [512][256]
    float*          bqkt  = (float*)(Wtp + 131072);                // [768]

    const dim3 blk(256);
    const int gb64 = (N + 63) / 64;
    const int eb   = min((P + 3) / 4, 2048);     // persistent: 2048 blocks = 8192 waves (full residency)

    // 1. weights prep
    prep_w<<<dim3(1024 + 512 + 3), blk, 0, stream>>>(
        Wq, Wk, W1, W2, Wpred, bq, bk, b1, Wtqkt, Wt2, Wtp, bqkt);

    // 2. fused node pipeline (y=0: q,k,t,g,gp ; y=1: hp), packed-table outputs
    gemm_fused<<<dim3(gb64, 2), blk, 0, stream>>>(
        z, h_mask, Wtqkt, Wt2, Wtp, bqkt, b2, qhp, kgp, N);

    // 3. edge phase (persistent grid-stride, nt stores)
    edge_fused<<<dim3(eb), blk, 0, stream>>>(qhp, kgp, bpred,
                                             edge_index, node_ids, masked_idx, edge_idx,
                                             (float*)d_out, P);
}

// Round 16
// 314.343 us; speedup vs baseline: 1.2208x; 1.2208x over previous
//
#include <hip/hip_runtime.h>
#include <hip/hip_bf16.h>

typedef __attribute__((ext_vector_type(8))) short s16x8;
typedef __attribute__((ext_vector_type(4))) float f32x4;
typedef __attribute__((ext_vector_type(2))) float f32x2;

__device__ inline unsigned int f2bf(float f) {
    union { float f; unsigned int i; } v;
    v.f = f;
    return (v.i + 0x7FFFu + ((v.i >> 16) & 1u)) >> 16;   // RNE
}
__device__ inline unsigned char f2fp8(float v) {
    const int p = __builtin_amdgcn_cvt_pk_fp8_f32(v, v, 0, false);
    return (unsigned char)(p & 0xFF);
}

// ---------- prep: weight transposes (bf16) + bias concat ----------
__global__ __launch_bounds__(256) void prep_w(
    const float* __restrict__ Wq, const float* __restrict__ Wk,
    const float* __restrict__ W1, const float* __restrict__ W2,
    const float* __restrict__ Wp,
    const float* __restrict__ bq, const float* __restrict__ bk,
    const float* __restrict__ b1,
    unsigned short* __restrict__ Wtqkt, unsigned short* __restrict__ Wt2,
    unsigned short* __restrict__ Wtp, float* __restrict__ bqkt)
{
    const int tid = threadIdx.x;
    int b = blockIdx.x;
    if (b < 1024) {                          // 4 x 256x256 weights
        const int w = b >> 8;
        const int i = (b & 255) * 256 + tid;
        const int k = i >> 8, j = i & 255;   // coalesced read of W[k][j]
        const float* W = (w == 0) ? Wq : (w == 1) ? Wk : (w == 2) ? W1 : W2;
        unsigned short* dst = (w == 3) ? Wt2 : (Wtqkt + w * 65536);
        dst[j * 256 + k] = (unsigned short)f2bf(W[i]);
        return;
    }
    b -= 1024;
    if (b < 512) {                           // Wpred [256][512] -> Wtp [512][256]
        const int i = b * 256 + tid;
        const int k = i >> 9, j = i & 511;
        Wtp[(size_t)j * 256 + k] = (unsigned short)f2bf(Wp[i]);
        return;
    }
    b -= 512;
    {                                        // bqkt = [bq | bk | b1]
        const int i = b * 256 + tid;
        bqkt[i] = (i < 256) ? bq[i] : (i < 512) ? bk[i - 256] : b1[i - 512];
    }
}

// ---------- fused node pipeline, one dispatch ----------
// Packed tables: qhp[N][768] = [q fp8 (256) | hp fp8 (512)]
//               kgp[N][768] = [k fp8 (256) | gp fp8 (512)]
// y=0: q,k = z@[Wq|Wk]+b; t = relu(z@W1+b1) [regs]; g = t@W2+b2 [regs->LDS];
//      gp = g@Wpred.  y=1: hp = h_mask@Wpred.
__global__ __launch_bounds__(256) void gemm_fused(
    const float* __restrict__ z, const float* __restrict__ h,
    const unsigned short* __restrict__ Wtqkt, const unsigned short* __restrict__ Wt2,
    const unsigned short* __restrict__ Wtp,
    const float* __restrict__ bqkt, const float* __restrict__ b2,
    unsigned char* __restrict__ qhp, unsigned char* __restrict__ kgp, int M)
{
    __shared__ __align__(16) char smem[65536];
    char* ldsA = smem;
    char* ldsB = smem + 32768;

    const int tid  = threadIdx.x;
    const int wid  = tid >> 6, lane = tid & 63;
    const int wr   = wid >> 1, wc = wid & 1;
    const int r0   = blockIdx.x * 64;
    const int swz  = (lane & 7) << 4;
    const int ro   = lane & 15, ko = (lane >> 4) * 16;
    const int lr0  = wr * 32 + (lane >> 4) * 4;       // local row base of C frags
    const int baseA0 = (wr * 32 +  0 + ro) * 512 + ko;
    const int baseA1 = (wr * 32 + 16 + ro) * 512 + ko;
    const int baseB0 = (wc * 32 +  0 + ro) * 512 + ko;
    const int baseB1 = (wc * 32 + 16 + ro) * 512 + ko;

    f32x4 a00, a01, a10, a11;

    auto stageAf = [&](const float* Af) {
        for (int i = tid; i < 2048; i += 256) {
            const int row = i >> 5, off = i & 31;
            const int gr = r0 + row;
            uint4 v = make_uint4(0, 0, 0, 0);
            if (gr < M) {
                const float4 a = *(const float4*)(Af + (size_t)gr * 256 + off * 8);
                const float4 c = *(const float4*)(Af + (size_t)gr * 256 + off * 8 + 4);
                v.x = f2bf(a.x) | (f2bf(a.y) << 16);
                v.y = f2bf(a.z) | (f2bf(a.w) << 16);
                v.z = f2bf(c.x) | (f2bf(c.y) << 16);
                v.w = f2bf(c.z) | (f2bf(c.w) << 16);
            }
            *(uint4*)(ldsA + ((row * 512 + off * 16) ^ ((row & 7) << 4))) = v;
        }
    };

    auto chunk = [&](const unsigned short* Wt, int rowbase) {
        for (int i = tid; i < 2048; i += 256) {
            const int row = i >> 5, off = i & 31;
            const uint4 v = *(const uint4*)(Wt + (size_t)(rowbase + row) * 256 + off * 8);
            *(uint4*)(ldsB + ((row * 512 + off * 16) ^ ((row & 7) << 4))) = v;
        }
        __syncthreads();
        a00 = (f32x4){0,0,0,0}; a01 = (f32x4){0,0,0,0};
        a10 = (f32x4){0,0,0,0}; a11 = (f32x4){0,0,0,0};
#pragma unroll
        for (int kk = 0; kk < 8; ++kk) {
            const int kb = kk * 64;
            const s16x8 x0 = *(const s16x8*)(ldsA + ((baseA0 + kb) ^ swz));
            const s16x8 x1 = *(const s16x8*)(ldsA + ((baseA1 + kb) ^ swz));
            const s16x8 y0 = *(const s16x8*)(ldsB + ((baseB0 + kb) ^ swz));
            const s16x8 y1 = *(const s16x8*)(ldsB + ((baseB1 + kb) ^ swz));
            a00 = __builtin_amdgcn_mfma_f32_16x16x32_bf16(x0, y0, a00, 0, 0, 0);
            a01 = __builtin_amdgcn_mfma_f32_16x16x32_bf16(x0, y1, a01, 0, 0, 0);
            a10 = __builtin_amdgcn_mfma_f32_16x16x32_bf16(x1, y0, a10, 0, 0, 0);
            a11 = __builtin_amdgcn_mfma_f32_16x16x32_bf16(x1, y1, a11, 0, 0, 0);
        }
    };

    auto store_fp8 = [&](unsigned char* outb, int obase, const float* bias) {
        const int cb = wc * 32;
        const float bs0 = bias ? bias[cb + ro] : 0.0f;
        const float bs1 = bias ? bias[cb + 16 + ro] : 0.0f;
        const int gr0 = r0 + lr0, gr1 = gr0 + 16;
        const int col0 = obase + cb + ro, col1 = obase + cb + 16 + ro;
#pragma unroll
        for (int r = 0; r < 4; ++r) {
            if (gr0 + r < M) {
                outb[(size_t)(gr0 + r) * 768 + col0] = f2fp8(a00[r] + bs0);
                outb[(size_t)(gr0 + r) * 768 + col1] = f2fp8(a01[r] + bs1);
            }
            if (gr1 + r < M) {
                outb[(size_t)(gr1 + r) * 768 + col0] = f2fp8(a10[r] + bs0);
                outb[(size_t)(gr1 + r) * 768 + col1] = f2fp8(a11[r] + bs1);
            }
        }
        __syncthreads();
    };

    auto frag_to_ldsA = [&](const unsigned int* treg) {
#pragma unroll
        for (int tc = 0; tc < 4; ++tc) {
            const int cb = tc * 64 + wc * 32;
#pragma unroll
            for (int r = 0; r < 4; ++r) {
                const unsigned int w0 = treg[tc * 8 + r * 2];
                const unsigned int w1 = treg[tc * 8 + r * 2 + 1];
                const int row0 = lr0 + r, row1 = row0 + 16;
                *(unsigned short*)(ldsA + ((row0 * 512 + (cb + ro) * 2)      ^ ((row0 & 7) << 4))) = (unsigned short)(w0 & 0xFFFFu);
                *(unsigned short*)(ldsA + ((row0 * 512 + (cb + 16 + ro) * 2) ^ ((row0 & 7) << 4))) = (unsigned short)(w0 >> 16);
                *(unsigned short*)(ldsA + ((row1 * 512 + (cb + ro) * 2)      ^ ((row1 & 7) << 4))) = (unsigned short)(w1 & 0xFFFFu);
                *(unsigned short*)(ldsA + ((row1 * 512 + (cb + 16 + ro) * 2) ^ ((row1 & 7) << 4))) = (unsigned short)(w1 >> 16);
            }
        }
    };

    if (blockIdx.y == 1) {
        stageAf(h);
        for (int c = 0; c < 8; ++c) { chunk(Wtp, c * 64); store_fp8(qhp, 256 + c * 64, nullptr); }
        return;
    }

    // ---- z-path ----
    stageAf(z);
    for (int c = 0; c < 4; ++c) { chunk(Wtqkt, c * 64);        store_fp8(qhp, c * 64, bqkt + c * 64); }
    for (int c = 0; c < 4; ++c) { chunk(Wtqkt, 256 + c * 64);  store_fp8(kgp, c * 64, bqkt + 256 + c * 64); }

    unsigned int treg[32];
#pragma unroll
    for (int tc = 0; tc < 4; ++tc) {
        chunk(Wtqkt, 512 + tc * 64);
        const int cb = tc * 64 + wc * 32;
        const float bs0 = bqkt[512 + cb + ro];
        const float bs1 = bqkt[512 + cb + 16 + ro];
#pragma unroll
        for (int r = 0; r < 4; ++r) {
            treg[tc * 8 + r * 2]     = f2bf(fmaxf(a00[r] + bs0, 0.0f)) | (f2bf(fmaxf(a01[r] + bs1, 0.0f)) << 16);
            treg[tc * 8 + r * 2 + 1] = f2bf(fmaxf(a10[r] + bs0, 0.0f)) | (f2bf(fmaxf(a11[r] + bs1, 0.0f)) << 16);
        }
        __syncthreads();
    }
    frag_to_ldsA(treg);
    __syncthreads();

#pragma unroll
    for (int gc = 0; gc < 4; ++gc) {
        chunk(Wt2, gc * 64);
        const int cb = gc * 64 + wc * 32;
        const float bs0 = b2[cb + ro];
        const float bs1 = b2[cb + 16 + ro];
#pragma unroll
        for (int r = 0; r < 4; ++r) {
            treg[gc * 8 + r * 2]     = f2bf(a00[r] + bs0) | (f2bf(a01[r] + bs1) << 16);
            treg[gc * 8 + r * 2 + 1] = f2bf(a10[r] + bs0) | (f2bf(a11[r] + bs1) << 16);
        }
        __syncthreads();
    }
    frag_to_ldsA(treg);
    __syncthreads();

    for (int c = 0; c < 8; ++c) { chunk(Wtp, c * 64); store_fp8(kgp, 256 + c * 64, nullptr); }
}

// ---------- edge kernel: one wave/edge, packed tables, nt stores ----------
// qhp row c: [q | hp]; kgp row s: [k | gp] — 2 random 768B regions per edge.
__global__ __launch_bounds__(256) void edge_fused(
    const unsigned char* __restrict__ qhp, const unsigned char* __restrict__ kgp,
    const float* __restrict__ bpred,
    const int* __restrict__ edge_src, const int* __restrict__ node_ids,
    const int* __restrict__ masked_idx, const int* __restrict__ edge_idx,
    float* __restrict__ out, int P)
{
    const int wave = threadIdx.x >> 6;
    const int lane = threadIdx.x & 63;
    const int e = blockIdx.x * 4 + wave;
    if (e >= P) return;

    const int mi = masked_idx[e];
    const int c  = node_ids[mi];
    const int s  = edge_src[edge_idx[e]];

    const unsigned char* rc = qhp + (size_t)c * 768;
    const unsigned char* rs = kgp + (size_t)s * 768;

    // dot(q[c], k[s]) — 4 fp8 elems/lane each
    const unsigned int qw = *(const unsigned int*)(rc + lane * 4);
    const unsigned int kw = *(const unsigned int*)(rs + lane * 4);
    const f32x2 q01 = __builtin_amdgcn_cvt_pk_f32_fp8(qw, false);
    const f32x2 q23 = __builtin_amdgcn_cvt_pk_f32_fp8(qw, true);
    const f32x2 k01 = __builtin_amdgcn_cvt_pk_f32_fp8(kw, false);
    const f32x2 k23 = __builtin_amdgcn_cvt_pk_f32_fp8(kw, true);
    float dot = q01.x * k01.x + q01.y * k01.y + q23.x * k23.x + q23.y * k23.y;
#pragma unroll
    for (int off = 32; off; off >>= 1) dot += __shfl_xor(dot, off, 64);

    const float a = 1.0f / (1.0f + expf(-dot));
    const float oma = 1.0f - a;

    // 8 outputs/lane
    const uint2 hv = *(const uint2*)(rc + 256 + lane * 8);
    const uint2 gv = *(const uint2*)(rs + 256 + lane * 8);
    const float4 bp0 = *(const float4*)&bpred[lane * 8];
    const float4 bp1 = *(const float4*)&bpred[lane * 8 + 4];

    const f32x2 h0 = __builtin_amdgcn_cvt_pk_f32_fp8(hv.x, false);
    const f32x2 h1 = __builtin_amdgcn_cvt_pk_f32_fp8(hv.x, true);
    const f32x2 h2 = __builtin_amdgcn_cvt_pk_f32_fp8(hv.y, false);
    const f32x2 h3 = __builtin_amdgcn_cvt_pk_f32_fp8(hv.y, true);
    const f32x2 g0 = __builtin_amdgcn_cvt_pk_f32_fp8(gv.x, false);
    const f32x2 g1 = __builtin_amdgcn_cvt_pk_f32_fp8(gv.x, true);
    const f32x2 g2 = __builtin_amdgcn_cvt_pk_f32_fp8(gv.y, false);
    const f32x2 g3 = __builtin_amdgcn_cvt_pk_f32_fp8(gv.y, true);

    f32x4 r0, r1;
    r0[0] = fmaf(a, h0.x, fmaf(oma, g0.x, bp0.x));
    r0[1] = fmaf(a, h0.y, fmaf(oma, g0.y, bp0.y));
    r0[2] = fmaf(a, h1.x, fmaf(oma, g1.x, bp0.z));
    r0[3] = fmaf(a, h1.y, fmaf(oma, g1.y, bp0.w));
    r1[0] = fmaf(a, h2.x, fmaf(oma, g2.x, bp1.x));
    r1[1] = fmaf(a, h2.y, fmaf(oma, g2.y, bp1.y));
    r1[2] = fmaf(a, h3.x, fmaf(oma, g3.x, bp1.z));
    r1[3] = fmaf(a, h3.y, fmaf(oma, g3.y, bp1.w));

    float* dst = &out[(size_t)e * 512 + lane * 8];
    __builtin_nontemporal_store(r0, (f32x4*)dst);
    __builtin_nontemporal_store(r1, (f32x4*)(dst + 4));

    if (lane == 0) {
        __builtin_nontemporal_store((float)mi, &out[(size_t)P * 512 + e]);
    }
}

extern "C" void kernel_launch(void* const* d_in, const int* in_sizes, int n_in,
                              void* d_out, int out_size, void* d_ws, size_t ws_size,
                              hipStream_t stream) {
    const float* h_mask = (const float*)d_in[0];
    const float* z      = (const float*)d_in[1];
    const float* Wq     = (const float*)d_in[2];
    const float* bq     = (const float*)d_in[3];
    const float* Wk     = (const float*)d_in[4];
    const float* bk     = (const float*)d_in[5];
    const float* W1     = (const float*)d_in[6];
    const float* b1     = (const float*)d_in[7];
    const float* W2     = (const float*)d_in[8];
    const float* b2     = (const float*)d_in[9];
    const float* Wpred  = (const float*)d_in[10];
    const float* bpred  = (const float*)d_in[11];
    const int* edge_index = (const int*)d_in[12];
    const int* node_ids   = (const int*)d_in[13];
    const int* masked_idx = (const int*)d_in[14];
    const int* edge_idx   = (const int*)d_in[15];

    const int N = in_sizes[13];
    const int P = in_sizes[14];

    // ---- workspace layout ----
    unsigned char*  qhp   = (unsigned char*)d_ws;                  // [N][768] fp8 = q|hp
    unsigned char*  kgp   = qhp + (size_t)N * 768;                 // [N][768] fp8 = k|gp
    unsigned short* Wtqkt = (unsigned short*)(kgp + (size_t)N * 768);  // [768][256] bf16
    unsigned short* Wt2   = Wtqkt + 196608;                        // [256][256]
    unsigned short* Wtp   = Wt2   + 65536;                         // [512][256]
    float*          bqkt  = (float*)(Wtp + 131072);                // [768]

    const dim3 blk(256);
    const int gb64 = (N + 63) / 64;
    const int eb   = (P + 3) / 4;

    // 1. weights prep
    prep_w<<<dim3(1024 + 512 + 3), blk, 0, stream>>>(
        Wq, Wk, W1, W2, Wpred, bq, bk, b1, Wtqkt, Wt2, Wtp, bqkt);

    // 2. fused node pipeline (y=0: q,k,t,g,gp ; y=1: hp), packed-table outputs
    gemm_fused<<<dim3(gb64, 2), blk, 0, stream>>>(
        z, h_mask, Wtqkt, Wt2, Wtp, bqkt, b2, qhp, kgp, N);

    // 3. edge phase (one wave/edge, 2 packed gathers, nt stores)
    edge_fused<<<dim3(eb), blk, 0, stream>>>(qhp, kgp, bpred,
                                             edge_index, node_ids, masked_idx, edge_idx,
                                             (float*)d_out, P);
}